// Round 7
// baseline (1114.718 us; speedup 1.0000x reference)
//
#include <hip/hip_runtime.h>

#define N_NODES 500000
#define N_EDGES 5000000
#define D 16

#define BSH 8                              // 256 nodes per dst-bucket
#define BN (1 << BSH)
#define NB ((N_NODES + BN - 1) >> BSH)     // 1954
#define AP 17                              // padded agg row stride (banks spread)
#define CHUNK 512
#define BIN_CHUNK 8192
#define NBIN_BLOCKS ((N_EDGES + BIN_CHUNK - 1) / BIN_CHUNK)  // 611

// ---------------------------------------------------------------------------
// 1) Per-DST-bucket edge counts (LDS histogram).
// ---------------------------------------------------------------------------
__global__ __launch_bounds__(256) void hist_kernel(
    const int* __restrict__ edge_index, int* __restrict__ cnt) {
    __shared__ int h[NB];
    for (int i = threadIdx.x; i < NB; i += 256) h[i] = 0;
    __syncthreads();
    int stride = gridDim.x * 256;
    for (int e = blockIdx.x * 256 + threadIdx.x; e < N_EDGES; e += stride)
        atomicAdd(&h[edge_index[N_EDGES + e] >> BSH], 1);   // dst row
    __syncthreads();
    for (int i = threadIdx.x; i < NB; i += 256)
        if (h[i]) atomicAdd(&cnt[i], h[i]);
}

// ---------------------------------------------------------------------------
// 2) Exclusive scan of NB counts (single block, 8/thread).
// ---------------------------------------------------------------------------
__global__ __launch_bounds__(256) void scan_kernel(
    const int* __restrict__ cnt, int* __restrict__ base, int* __restrict__ cursor) {
    __shared__ int sums[256];
    int t = threadIdx.x;
    int v[8]; int ts = 0;
    #pragma unroll
    for (int j = 0; j < 8; ++j) {
        int i = t * 8 + j;
        v[j] = (i < NB) ? cnt[i] : 0;
        ts += v[j];
    }
    sums[t] = ts;
    __syncthreads();
    for (int off = 1; off < 256; off <<= 1) {
        int val = (t >= off) ? sums[t - off] : 0;
        __syncthreads();
        if (t >= off) sums[t] += val;
        __syncthreads();
    }
    int p = sums[t] - ts;
    #pragma unroll
    for (int j = 0; j < 8; ++j) {
        int i = t * 8 + j;
        if (i < NB) { base[i] = p; cursor[i] = p; }
        p += v[j];
    }
    if (t == 255) base[NB] = p;   // = N_EDGES
}

// ---------------------------------------------------------------------------
// 3) LDS-staged binning by DST bucket, coalesced run write-out.
//    Entry = (src 19b) << 8 | dst_local (8b).
// ---------------------------------------------------------------------------
__global__ __launch_bounds__(256) void bin_kernel(
    const int* __restrict__ edge_index, int* __restrict__ cursor,
    unsigned int* __restrict__ binned) {
    __shared__ unsigned int buf[BIN_CHUNK];        // 32 KB
    __shared__ unsigned short bufB[BIN_CHUNK];     // 16 KB
    __shared__ int hist[NB];
    __shared__ int lofs[NB];
    __shared__ int gofs[NB];
    __shared__ int sums[256];

    int t = threadIdx.x;
    int start = blockIdx.x * BIN_CHUNK;
    int count = min(BIN_CHUNK, N_EDGES - start);

    for (int i = t; i < NB; i += 256) hist[i] = 0;
    __syncthreads();
    for (int k = t; k < count; k += 256)
        atomicAdd(&hist[edge_index[N_EDGES + start + k] >> BSH], 1);
    __syncthreads();

    int v[8]; int ts = 0;
    #pragma unroll
    for (int j = 0; j < 8; ++j) {
        int i = t * 8 + j;
        v[j] = (i < NB) ? hist[i] : 0;
        ts += v[j];
    }
    sums[t] = ts;
    __syncthreads();
    for (int off = 1; off < 256; off <<= 1) {
        int val = (t >= off) ? sums[t - off] : 0;
        __syncthreads();
        if (t >= off) sums[t] += val;
        __syncthreads();
    }
    int p = sums[t] - ts;
    #pragma unroll
    for (int j = 0; j < 8; ++j) {
        int i = t * 8 + j;
        if (i < NB) lofs[i] = p;
        p += v[j];
    }
    __syncthreads();

    for (int i = t; i < NB; i += 256) {
        int c = hist[i];
        gofs[i] = c ? atomicAdd(&cursor[i], c) : 0;
    }
    __syncthreads();
    for (int i = t; i < NB; i += 256) hist[i] = lofs[i];
    __syncthreads();

    for (int k = t; k < count; k += 256) {
        int s = edge_index[start + k];
        int d = edge_index[N_EDGES + start + k];
        int b = d >> BSH;
        int pos = atomicAdd(&hist[b], 1);
        buf[pos] = ((unsigned int)s << 8) | (unsigned int)(d & (BN - 1));
        bufB[pos] = (unsigned short)b;
    }
    __syncthreads();

    for (int i = t; i < count; i += 256) {
        int b = bufB[i];
        binned[gofs[b] + (i - lofs[b])] = buf[i];
    }
}

// ---------------------------------------------------------------------------
// 4) Fused layer 1: pull-based. Block owns one dst-bucket (256 nodes).
//    Stage edge entries in LDS; 16-lane groups gather x[src] rows (one 64B
//    line per edge, unroll-2 for MLP) and accumulate into padded LDS agg
//    (non-atomic w.r.t. global). Then per-thread node transform + ReLU.
// ---------------------------------------------------------------------------
__global__ __launch_bounds__(256) void layer1_kernel(
    const float* __restrict__ x,
    const unsigned int* __restrict__ binned,
    const int* __restrict__ base,
    const float* __restrict__ w_rel, const float* __restrict__ b_rel,
    const float* __restrict__ w_root,
    float* __restrict__ h1) {
    __shared__ float agg[BN * AP];                 // 17 KB, padded
    __shared__ float sWrelT[D * D], sWrootT[D * D], sB[D];
    __shared__ unsigned int sE[CHUNK];             // 2 KB
    int t = threadIdx.x;
    {
        int r = t >> 4, c = t & 15;
        sWrelT[c * D + r] = w_rel[r * D + c];
        sWrootT[c * D + r] = w_root[r * D + c];
        if (t < D) sB[t] = b_rel[t];
    }
    for (int i = t; i < BN * AP; i += 256) agg[i] = 0.f;
    __syncthreads();

    int bkt = blockIdx.x;
    int e0 = base[bkt], e1 = base[bkt + 1];
    int g = t >> 4, j = t & 15;

    for (int c0 = e0; c0 < e1; c0 += CHUNK) {
        int m = min(CHUNK, e1 - c0);
        for (int i = t; i < m; i += 256) sE[i] = binned[c0 + i];
        __syncthreads();
        int i = g;
        for (; i + 16 < m; i += 32) {
            unsigned int u0 = sE[i], u1 = sE[i + 16];
            float v0 = x[(long)(u0 >> 8) * D + j];      // 64B line per group
            float v1 = x[(long)(u1 >> 8) * D + j];
            atomicAdd(&agg[(u0 & (BN - 1)) * AP + j], v0);
            atomicAdd(&agg[(u1 & (BN - 1)) * AP + j], v1);
        }
        if (i < m) {
            unsigned int u0 = sE[i];
            atomicAdd(&agg[(u0 & (BN - 1)) * AP + j], x[(long)(u0 >> 8) * D + j]);
        }
        __syncthreads();
    }

    // node transform: one thread per node
    int node = (bkt << BSH) + t;
    if (t < BN && node < N_NODES) {
        float a[D], xi[D];
        #pragma unroll
        for (int k = 0; k < D; ++k) a[k] = agg[t * AP + k];
        const float4* xp = (const float4*)(x + (long)node * D);
        #pragma unroll
        for (int q = 0; q < 4; ++q) {
            float4 xv = xp[q];
            xi[q * 4 + 0] = xv.x; xi[q * 4 + 1] = xv.y;
            xi[q * 4 + 2] = xv.z; xi[q * 4 + 3] = xv.w;
        }
        float4* hp = (float4*)(h1 + (long)node * D);
        #pragma unroll
        for (int q = 0; q < 4; ++q) {
            float4 o;
            float* op = &o.x;
            #pragma unroll
            for (int r = 0; r < 4; ++r) {
                int dd = q * 4 + r;
                float acc = sB[dd];
                #pragma unroll
                for (int k = 0; k < D; ++k)
                    acc += a[k] * sWrelT[k * D + dd] + xi[k] * sWrootT[k * D + dd];
                op[r] = acc > 0.f ? acc : 0.f;
            }
            hp[q] = o;
        }
    }
}

// ---------------------------------------------------------------------------
// 5) Fused layer 2 + head (same structure; gathers from h1; emits out).
// ---------------------------------------------------------------------------
__global__ __launch_bounds__(256) void layer2_kernel(
    const float* __restrict__ h1,
    const unsigned int* __restrict__ binned,
    const int* __restrict__ base,
    const float* __restrict__ w_rel, const float* __restrict__ b_rel,
    const float* __restrict__ w_root,
    const float* __restrict__ fc1_w, const float* __restrict__ fc1_b,
    const float* __restrict__ fc2_w, const float* __restrict__ fc2_b,
    float* __restrict__ out) {
    __shared__ float agg[BN * AP];
    __shared__ float sWrelT[D * D], sWrootT[D * D], sB[D];
    __shared__ float sF1w[8 * D], sF1b[8], sF2w[2 * 8], sF2b[2];
    __shared__ unsigned int sE[CHUNK];
    int t = threadIdx.x;
    {
        int r = t >> 4, c = t & 15;
        sWrelT[c * D + r] = w_rel[r * D + c];
        sWrootT[c * D + r] = w_root[r * D + c];
        if (t < D) sB[t] = b_rel[t];
        if (t < 8 * D) sF1w[t] = fc1_w[t];
        if (t < 8) sF1b[t] = fc1_b[t];
        if (t < 16) sF2w[t] = fc2_w[t];
        if (t < 2) sF2b[t] = fc2_b[t];
    }
    for (int i = t; i < BN * AP; i += 256) agg[i] = 0.f;
    __syncthreads();

    int bkt = blockIdx.x;
    int e0 = base[bkt], e1 = base[bkt + 1];
    int g = t >> 4, j = t & 15;

    for (int c0 = e0; c0 < e1; c0 += CHUNK) {
        int m = min(CHUNK, e1 - c0);
        for (int i = t; i < m; i += 256) sE[i] = binned[c0 + i];
        __syncthreads();
        int i = g;
        for (; i + 16 < m; i += 32) {
            unsigned int u0 = sE[i], u1 = sE[i + 16];
            float v0 = h1[(long)(u0 >> 8) * D + j];
            float v1 = h1[(long)(u1 >> 8) * D + j];
            atomicAdd(&agg[(u0 & (BN - 1)) * AP + j], v0);
            atomicAdd(&agg[(u1 & (BN - 1)) * AP + j], v1);
        }
        if (i < m) {
            unsigned int u0 = sE[i];
            atomicAdd(&agg[(u0 & (BN - 1)) * AP + j], h1[(long)(u0 >> 8) * D + j]);
        }
        __syncthreads();
    }

    int node = (bkt << BSH) + t;
    if (t < BN && node < N_NODES) {
        float a[D], xi[D];
        #pragma unroll
        for (int k = 0; k < D; ++k) a[k] = agg[t * AP + k];
        const float4* xp = (const float4*)(h1 + (long)node * D);
        #pragma unroll
        for (int q = 0; q < 4; ++q) {
            float4 xv = xp[q];
            xi[q * 4 + 0] = xv.x; xi[q * 4 + 1] = xv.y;
            xi[q * 4 + 2] = xv.z; xi[q * 4 + 3] = xv.w;
        }
        float h2[D];
        #pragma unroll
        for (int dd = 0; dd < D; ++dd) {
            float acc = sB[dd];
            #pragma unroll
            for (int k = 0; k < D; ++k)
                acc += a[k] * sWrelT[k * D + dd] + xi[k] * sWrootT[k * D + dd];
            h2[dd] = acc > 0.f ? acc : 0.f;
        }
        float h3[8];
        #pragma unroll
        for (int jj = 0; jj < 8; ++jj) {
            float acc = sF1b[jj];
            #pragma unroll
            for (int k = 0; k < D; ++k) acc += h2[k] * sF1w[jj * D + k];
            h3[jj] = acc > 0.f ? acc : 0.f;
        }
        float2 o;
        float acc0 = sF2b[0], acc1 = sF2b[1];
        #pragma unroll
        for (int jj = 0; jj < 8; ++jj) {
            acc0 += h3[jj] * sF2w[0 * 8 + jj];
            acc1 += h3[jj] * sF2w[1 * 8 + jj];
        }
        o.x = acc0; o.y = acc1;
        ((float2*)out)[node] = o;
    }
}

extern "C" void kernel_launch(void* const* d_in, const int* in_sizes, int n_in,
                              void* d_out, int out_size, void* d_ws, size_t ws_size,
                              hipStream_t stream) {
    const float* x          = (const float*)d_in[0];
    const int*   edge_index = (const int*)d_in[1];
    const float* c1_wrel    = (const float*)d_in[2];
    const float* c1_brel    = (const float*)d_in[3];
    const float* c1_wroot   = (const float*)d_in[4];
    const float* c2_wrel    = (const float*)d_in[5];
    const float* c2_brel    = (const float*)d_in[6];
    const float* c2_wroot   = (const float*)d_in[7];
    const float* fc1_w      = (const float*)d_in[8];
    const float* fc1_b      = (const float*)d_in[9];
    const float* fc2_w      = (const float*)d_in[10];
    const float* fc2_b      = (const float*)d_in[11];
    float* out = (float*)d_out;

    // Workspace: binned 20 MB | h1 32 MB | cnt/base/cursor ~24 KB
    unsigned int* binned = (unsigned int*)d_ws;
    float* h1   = (float*)(binned + N_EDGES);
    int* cnt    = (int*)(h1 + (size_t)N_NODES * D);
    int* base   = cnt + NB;
    int* cursor = base + (NB + 1);

    // --- Build dst-binned edge list (amortized over both layers) ---
    hipMemsetAsync(cnt, 0, NB * sizeof(int), stream);
    hist_kernel<<<1024, 256, 0, stream>>>(edge_index, cnt);
    scan_kernel<<<1, 256, 0, stream>>>(cnt, base, cursor);
    bin_kernel<<<NBIN_BLOCKS, 256, 0, stream>>>(edge_index, cursor, binned);

    // --- Fused layers (no global atomics, no agg round-trips) ---
    layer1_kernel<<<NB, 256, 0, stream>>>(
        x, binned, base, c1_wrel, c1_brel, c1_wroot, h1);
    layer2_kernel<<<NB, 256, 0, stream>>>(
        h1, binned, base, c2_wrel, c2_brel, c2_wroot,
        fc1_w, fc1_b, fc2_w, fc2_b, out);
}